// Round 10
// baseline (102.733 us; speedup 1.0000x reference)
//
#include <hip/hip_runtime.h>

#define NP 128      // proposals
#define NB 16       // neighbors per proposal
#define KK 64       // knn per node
#define LL 1024     // NB*KK
#define MM 450      // FINEMATCH_MAX_POINT
#define DD 256      // feat dim
#define CHUNKS 16   // row-chunks per proposal (2048 blocks = 8/CU, 32 waves/CU)
#define ROWS 29     // ceil(MM / CHUNKS)

typedef float f32x4 __attribute__((ext_vector_type(4)));

// Probe whether bool inputs are packed uint8 (1B) or int32 (4B).
// (R5/R7 evidence: int32 on this harness; probe kept — cheap, branch-uniform.)
__device__ __forceinline__ bool probe_is_u8(const void* nb_mask_raw) {
    const unsigned int* w = (const unsigned int*)nb_mask_raw;
    bool u8 = false;
#pragma unroll
    for (int q = 0; q < 16; ++q) u8 |= (w[q] > 1u);
    return u8;
}

__device__ __forceinline__ int read_bool(const void* buf, int idx, bool is_u8) {
    if (is_u8) return ((const unsigned char*)buf)[idx] != 0;
    return ((const int*)buf)[idx] != 0;
}

// ---------------------------------------------------------------------------
// Fused kernel: block (p, chunk) does ballot-based compaction in LDS, then
// streams its 29 output rows. Feat stores NONTEMPORAL (60 MB write-once
// stream keeps the 20.5 MB feat table in L2). Stream loop holds 4 rows in
// flight per wave to hide L2-miss/LLC latency of the random row gathers.
// ---------------------------------------------------------------------------
__global__ __launch_bounds__(256) void n2p_fused(
    const void*  __restrict__ nb_mask_raw,   // [NP,NB] bool
    const int*   __restrict__ seed_idx,      // [NP,NB] int32
    const void*  __restrict__ knn_mask_raw,  // [NNODES,KK] bool
    const float* __restrict__ knn_pts,       // [NNODES,KK,3]
    const int*   __restrict__ knn_idx,       // [NNODES,KK]
    const float* __restrict__ feats,         // [NPTS,DD]
    float* __restrict__ out_pts,             // [NP,MM,3]
    float* __restrict__ out_feats,           // [NP,MM,DD]
    float* __restrict__ out_mask)            // [NP,MM]
{
    const int p     = blockIdx.x;
    const int chunk = blockIdx.y;
    const int t     = threadIdx.x;
    const int wv    = t >> 6;
    const int ln    = t & 63;

    __shared__ int s_node[NB];
    __shared__ int s_order[LL];   // valid l's, in order
    __shared__ int s_wsum[4];     // per-wave valid counts
    __shared__ int s_fidx[ROWS];  // per-row feat index (-1 => zero row)

    const bool is_u8 = probe_is_u8(nb_mask_raw);

    if (t < NB) s_node[t] = seed_idx[p * NB + t];
    __syncthreads();

    // ---- compaction: l = wv*256 + q*64 + ln; rank via ballot+popc ----
    int v[4];
#pragma unroll
    for (int q = 0; q < 4; ++q) {
        const int nbi  = wv * 4 + q;               // wave-uniform
        const int node = s_node[nbi];
        const int m_nb = read_bool(nb_mask_raw, p * NB + nbi, is_u8);
        const int m_kn = read_bool(knn_mask_raw, node * KK + ln, is_u8);
        v[q] = m_nb && m_kn;
    }
    const unsigned long long lt = (1ULL << ln) - 1ULL;
    int my_rank[4];
    int wtot = 0;
#pragma unroll
    for (int q = 0; q < 4; ++q) {
        const unsigned long long b = __ballot(v[q] != 0);
        my_rank[q] = wtot + __popcll(b & lt);
        wtot += __popcll(b);
    }
    if (ln == 0) s_wsum[wv] = wtot;
    __syncthreads();

    int wave_off = 0;
    for (int w2 = 0; w2 < wv; ++w2) wave_off += s_wsum[w2];
    const int n_total = s_wsum[0] + s_wsum[1] + s_wsum[2] + s_wsum[3];
#pragma unroll
    for (int q = 0; q < 4; ++q) {
        if (v[q]) s_order[wave_off + my_rank[q]] = wv * 256 + q * 64 + ln;
    }
    __syncthreads();

    // ---- per-row index precompute + pts/mask writes ----
    const int row0  = chunk * ROWS;
    const int nrows = (MM - row0 < ROWS) ? (MM - row0) : ROWS;
    const int n_eff = (n_total < MM) ? n_total : MM;

    if (t < nrows) {
        const int i = row0 + t;
        int src = -1, fidx = -1;
        if (i < n_eff) {
            // exact floor(i*n/450) — bit-exact contract vs np reference (R6)
            const int j = (n_total > MM) ? (int)((unsigned)(i * n_total) / (unsigned)MM)
                                         : i;
            const int l    = s_order[j];
            const int node = s_node[l >> 6];
            src  = node * KK + (l & 63);
            fidx = knn_idx[src];
        }
        s_fidx[t] = fidx;

        const size_t row = (size_t)p * MM + i;
        if (src >= 0) {
            out_pts[row * 3 + 0] = knn_pts[(size_t)src * 3 + 0];
            out_pts[row * 3 + 1] = knn_pts[(size_t)src * 3 + 1];
            out_pts[row * 3 + 2] = knn_pts[(size_t)src * 3 + 2];
            out_mask[row] = 1.0f;
        } else {
            out_pts[row * 3 + 0] = 0.0f;
            out_pts[row * 3 + 1] = 0.0f;
            out_pts[row * 3 + 2] = 0.0f;
            out_mask[row] = 0.0f;
        }
    }
    __syncthreads();

    // ---- streaming feat copy: wave per row, 4 rows in flight, nt stores ----
    const float* base_out = out_feats + ((size_t)p * MM + row0) * DD;
    int r = wv;
    for (; r + 12 < nrows; r += 16) {
        const int f0 = s_fidx[r];
        const int f1 = s_fidx[r + 4];
        const int f2 = s_fidx[r + 8];
        const int f3 = s_fidx[r + 12];
        const int c0 = (f0 >= 0) ? f0 : 0;
        const int c1 = (f1 >= 0) ? f1 : 0;
        const int c2 = (f2 >= 0) ? f2 : 0;
        const int c3 = (f3 >= 0) ? f3 : 0;
        f32x4 a = reinterpret_cast<const f32x4*>(feats + (size_t)c0 * DD)[ln];
        f32x4 b = reinterpret_cast<const f32x4*>(feats + (size_t)c1 * DD)[ln];
        f32x4 c = reinterpret_cast<const f32x4*>(feats + (size_t)c2 * DD)[ln];
        f32x4 d = reinterpret_cast<const f32x4*>(feats + (size_t)c3 * DD)[ln];
        if (f0 < 0) a = (f32x4)(0.f);
        if (f1 < 0) b = (f32x4)(0.f);
        if (f2 < 0) c = (f32x4)(0.f);
        if (f3 < 0) d = (f32x4)(0.f);
        __builtin_nontemporal_store(a, (f32x4*)(base_out + (size_t)r * DD) + ln);
        __builtin_nontemporal_store(b, (f32x4*)(base_out + (size_t)(r + 4) * DD) + ln);
        __builtin_nontemporal_store(c, (f32x4*)(base_out + (size_t)(r + 8) * DD) + ln);
        __builtin_nontemporal_store(d, (f32x4*)(base_out + (size_t)(r + 12) * DD) + ln);
    }
    for (; r < nrows; r += 4) {
        const int f0 = s_fidx[r];
        const int c0 = (f0 >= 0) ? f0 : 0;
        f32x4 a = reinterpret_cast<const f32x4*>(feats + (size_t)c0 * DD)[ln];
        if (f0 < 0) a = (f32x4)(0.f);
        __builtin_nontemporal_store(a, (f32x4*)(base_out + (size_t)r * DD) + ln);
    }
}

extern "C" void kernel_launch(void* const* d_in, const int* in_sizes, int n_in,
                              void* d_out, int out_size, void* d_ws, size_t ws_size,
                              hipStream_t stream) {
    const void*  nb_mask  = d_in[0];                // [128,16] bool (probed layout)
    const int*   seed_idx = (const int*)d_in[1];    // [128,16]
    const void*  knn_mask = d_in[2];                // [512,64] bool
    const float* knn_pts  = (const float*)d_in[3];  // [512,64,3] f32
    const int*   knn_idx  = (const int*)d_in[4];    // [512,64]
    const float* feats    = (const float*)d_in[5];  // [20000,256] f32

    float* out_pts   = (float*)d_out;                     // [128,450,3]
    float* out_feats = out_pts + (size_t)NP * MM * 3;     // [128,450,256]
    float* out_mask  = out_feats + (size_t)NP * MM * DD;  // [128,450]

    n2p_fused<<<dim3(NP, CHUNKS), dim3(256), 0, stream>>>(
        nb_mask, seed_idx, knn_mask, knn_pts, knn_idx, feats,
        out_pts, out_feats, out_mask);
}